// Round 2
// baseline (100.609 us; speedup 1.0000x reference)
//
#include <hip/hip_runtime.h>
#include <math.h>

#define N 384
#define DF 128
#define TI 16
#define TK 16
#define TEMP 2.0f
#define SOFT_LAMBDA 0.5f
#define BETA 1.0f
#define EPS_COS 1e-8f
#define EPS_LOG 1e-7f

// Workspace layout: [0] double acc_h, [8] double acc_t, [16] uint done_cnt,
// pk table at byte offset 256.

// ---------------------------------------------------------------------------
// Kernel A: pairwise table pk[i][k] = {td, rd, eo (0 on diag), lo}.
// 24x24 blocks of 16x16 pairs, 256 threads. Feature rows staged in LDS
// (rows padded to 33 float4 to break bank alignment). GEMM-shaped:
// coalesced, high occupancy, all latency hidden. (Round-0 proven version.)
// Block (0,0) additionally zeroes the cross-kernel accumulators.
// ---------------------------------------------------------------------------
__global__ __launch_bounds__(256) void rnc_pairs(
    const float* __restrict__ feat,   // [N, DF]
    const float* __restrict__ rg,     // [N, 3]
    const float* __restrict__ rr,     // [N, 3]
    const float* __restrict__ tr,     // [N, 3]
    const int*   __restrict__ sym,    // [N]
    float4* __restrict__ pk,          // [N*N]
    double* __restrict__ acc,         // [2]: acc_h, acc_t
    unsigned* __restrict__ done_cnt)
{
    const int i0 = blockIdx.y * TI;
    const int k0 = blockIdx.x * TK;
    const int t = threadIdx.x;

    if (blockIdx.x == 0 && blockIdx.y == 0 && t == 0) {
        acc[0] = 0.0;
        acc[1] = 0.0;
        *done_cnt = 0u;
    }

    __shared__ __align__(16) float4 fi_s[TI][DF / 4 + 1];  // +1 f4 pad
    __shared__ __align__(16) float4 fk_s[TK][DF / 4 + 1];
    __shared__ float4 hi_s[TI], gi_s[TI], ri_s[TI];  // trans+sym, rg+norm, rr+norm
    __shared__ float4 hk_s[TK], gk_s[TK], rk_s[TK];

    if (t < TI) {
        int g = i0 + t;
        hi_s[t] = make_float4(tr[g * 3], tr[g * 3 + 1], tr[g * 3 + 2],
                              (sym[g] == 1) ? 1.f : 0.f);
        float a = rg[g * 3], b = rg[g * 3 + 1], c = rg[g * 3 + 2];
        gi_s[t] = make_float4(a, b, c, fmaxf(sqrtf(a * a + b * b + c * c), EPS_COS));
        float d = rr[g * 3], e = rr[g * 3 + 1], f = rr[g * 3 + 2];
        ri_s[t] = make_float4(d, e, f, fmaxf(sqrtf(d * d + e * e + f * f), EPS_COS));
    } else if (t >= 32 && t < 32 + TK) {
        int g = k0 + (t - 32);
        int tl = t - 32;
        hk_s[tl] = make_float4(tr[g * 3], tr[g * 3 + 1], tr[g * 3 + 2],
                               (sym[g] == 1) ? 1.f : 0.f);
        float a = rg[g * 3], b = rg[g * 3 + 1], c = rg[g * 3 + 2];
        gk_s[tl] = make_float4(a, b, c, fmaxf(sqrtf(a * a + b * b + c * c), EPS_COS));
        float d = rr[g * 3], e = rr[g * 3 + 1], f = rr[g * 3 + 2];
        rk_s[tl] = make_float4(d, e, f, fmaxf(sqrtf(d * d + e * e + f * f), EPS_COS));
    }

    const float4* feat4 = reinterpret_cast<const float4*>(feat);
#pragma unroll
    for (int idx = 0; idx < 2; ++idx) {
        int u = t + idx * 256;            // 0..511 over 16 rows x 32 f4
        int row = u >> 5, c = u & 31;
        fi_s[row][c] = feat4[(i0 + row) * (DF / 4) + c];
        fk_s[row][c] = feat4[(k0 + row) * (DF / 4) + c];
    }
    __syncthreads();

    const int ii = t >> 4, kk = t & 15;
    float sq = 0.f;
#pragma unroll
    for (int d = 0; d < DF / 4; ++d) {
        float4 a = fi_s[ii][d];
        float4 b = fk_s[kk][d];
        float dx = a.x - b.x, dy = a.y - b.y, dz = a.z - b.z, dw = a.w - b.w;
        sq += dx * dx + dy * dy + dz * dz + dw * dw;
    }
    const int gi = i0 + ii, gk = k0 + kk;
    float dist = (sq > 0.f) ? sqrtf(sq) : 0.f;
    float lo = -dist * (1.0f / TEMP);
    float eo = (gi == gk) ? 0.f : expf(lo);

    float4 ha = hi_s[ii], hb = hk_s[kk];
    float s = 0.f;
    {
        float d0 = ha.x - hb.x, d1 = ha.y - hb.y, d2 = ha.z - hb.z;
        float a0 = fabsf(d0), a1 = fabsf(d1), a2 = fabsf(d2);
        s += (a0 < BETA) ? (0.5f * d0 * d0 / BETA) : (a0 - 0.5f * BETA);
        s += (a1 < BETA) ? (0.5f * d1 * d1 / BETA) : (a1 - 0.5f * BETA);
        s += (a2 < BETA) ? (0.5f * d2 * d2 / BETA) : (a2 - 0.5f * BETA);
    }
    float td = s * (1.0f / 3.0f);

    float4 ga = gi_s[ii], gb = gk_s[kk];
    float gdiff = 1.0f - (ga.x * gb.x + ga.y * gb.y + ga.z * gb.z) / (ga.w * gb.w);
    float4 ra = ri_s[ii], rb = rk_s[kk];
    float rdiff = 1.0f - (ra.x * rb.x + ra.y * rb.y + ra.z * rb.z) / (ra.w * rb.w);
    bool pair_sym = (ha.w != 0.f) || (hb.w != 0.f);
    float rd = pair_sym ? gdiff : (gdiff + rdiff);

    pk[gi * N + gk] = make_float4(td, rd, eo, lo);
}

// ---------------------------------------------------------------------------
// Kernel B: rank denominators + pos terms + final reduction (fused).
// 768 blocks (row i = b>>1, j-half h = b&1) x 512 threads (8 waves). Lane l
// holds 3 j's in registers; wave w covers k in [w*48, w*48+48). One broadcast
// ds_read_b128 per k serves 6 accumulator chains. Block partials flow through
// device-scope double atomics; the last block (atomic ticket) writes out.
// ---------------------------------------------------------------------------
__global__ __launch_bounds__(512) void rnc_rank(
    const float4* __restrict__ pk,
    double* __restrict__ acc,         // [2]: acc_h, acc_t
    unsigned* __restrict__ done_cnt,
    float* __restrict__ out)
{
    const int i = blockIdx.x >> 1;
    const int h = blockIdx.x & 1;
    const int t = threadIdx.x;

    __shared__ __align__(16) float4 pks[N];      // 6 KB
    __shared__ __align__(16) float2 dp[192][8];  // 12 KB: [j_local][wave]
    __shared__ float red_h[8], red_t[8];

    if (t < N) pks[t] = pk[i * N + t];
    __syncthreads();

    const int w = t >> 6, l = t & 63;
    const int jl = l * 3;                 // local j base 0..189
    float tdj[3], rdj[3];
    float dent[3] = {0.f, 0.f, 0.f};
    float denh[3] = {0.f, 0.f, 0.f};
#pragma unroll
    for (int jj = 0; jj < 3; ++jj) {
        float4 p = pks[h * 192 + jl + jj];
        tdj[jj] = p.x;
        rdj[jj] = p.y;
    }
    const int k0 = w * 48;
#pragma unroll 4
    for (int k = k0; k < k0 + 48; ++k) {
        float4 p = pks[k];  // wave-uniform -> broadcast
#pragma unroll
        for (int jj = 0; jj < 3; ++jj) {
            bool mt = p.x >= tdj[jj];
            bool mh = mt && (p.y >= rdj[jj]);
            dent[jj] += mt ? p.z : 0.f;
            denh[jj] += mh ? p.z : 0.f;
        }
    }
#pragma unroll
    for (int jj = 0; jj < 3; ++jj) dp[jl + jj][w] = make_float2(dent[jj], denh[jj]);
    __syncthreads();

    float pos_h = 0.f, pos_t = 0.f;
    if (t < 192) {
        const int j = h * 192 + t;
        if (j != i) {
            float st_ = 0.f, sh_ = 0.f;
#pragma unroll
            for (int g = 0; g < 8; ++g) {
                float2 v = dp[t][g];
                st_ += v.x;
                sh_ += v.y;
            }
            float lo = pks[j].w;
            pos_h = lo - logf(sh_ + EPS_LOG);
            pos_t = lo - logf(st_ + EPS_LOG);
        }
    }
#pragma unroll
    for (int off = 32; off > 0; off >>= 1) {
        pos_h += __shfl_down(pos_h, off, 64);
        pos_t += __shfl_down(pos_t, off, 64);
    }
    if (l == 0) {
        red_h[w] = pos_h;
        red_t[w] = pos_t;
    }
    __syncthreads();
    if (t == 0) {
        float sh = 0.f, st = 0.f;
#pragma unroll
        for (int g = 0; g < 8; ++g) {
            sh += red_h[g];
            st += red_t[g];
        }
        atomicAdd(&acc[0], (double)sh);
        atomicAdd(&acc[1], (double)st);
        __threadfence();
        unsigned prev = atomicAdd(done_cnt, 1u);
        if (prev == 2u * N - 1u) {
            // All 768 blocks' value-adds precede their ticket (program order +
            // fence); atomics are device-coherent, so these reads see the
            // complete sums.
            double fh = atomicAdd(&acc[0], 0.0);
            double ft = atomicAdd(&acc[1], 0.0);
            const double denom = (double)N * (double)(N - 1);
            out[0] = (float)(-(fh + (double)SOFT_LAMBDA * ft) / denom);
        }
    }
}

extern "C" void kernel_launch(void* const* d_in, const int* in_sizes, int n_in,
                              void* d_out, int out_size, void* d_ws, size_t ws_size,
                              hipStream_t stream) {
    const float* feat = (const float*)d_in[0];  // [384,128]
    const float* rg   = (const float*)d_in[1];  // [384,3]
    const float* rr   = (const float*)d_in[2];  // [384,3]
    const float* tr   = (const float*)d_in[3];  // [384,3]
    const int*   sym  = (const int*)d_in[4];    // [384,1]
    float* out = (float*)d_out;

    double*   acc      = (double*)d_ws;                       // 2 doubles
    unsigned* done_cnt = (unsigned*)((char*)d_ws + 16);
    float4*   pk       = (float4*)((char*)d_ws + 256);        // 384*384*16 B

    dim3 gridA(N / TK, N / TI);
    rnc_pairs<<<gridA, 256, 0, stream>>>(feat, rg, rr, tr, sym, pk, acc, done_cnt);
    rnc_rank<<<2 * N, 512, 0, stream>>>(pk, acc, done_cnt, out);
}

// Round 3
// 79.497 us; speedup vs baseline: 1.2656x; 1.2656x over previous
//
#include <hip/hip_runtime.h>
#include <math.h>

#define N 384
#define DF 128
#define TI 16
#define TK 16
#define TEMP 2.0f
#define SOFT_LAMBDA 0.5f
#define BETA 1.0f
#define EPS_COS 1e-8f
#define EPS_LOG 1e-7f

// ---------------------------------------------------------------------------
// Kernel A: pairwise table pk[i][k] = {td, rd, eo (0 on diag), lo}.
// 24x24 blocks of 16x16 pairs, 256 threads. Feature rows staged in LDS
// (rows padded to 33 float4 = stride 132 floats to break bank alignment).
// GEMM-shaped: high occupancy, all latency well hidden.
// ---------------------------------------------------------------------------
__global__ __launch_bounds__(256) void rnc_pairs(
    const float* __restrict__ feat,   // [N, DF]
    const float* __restrict__ rg,     // [N, 3]
    const float* __restrict__ rr,     // [N, 3]
    const float* __restrict__ tr,     // [N, 3]
    const int*   __restrict__ sym,    // [N]
    float4* __restrict__ pk)          // [N*N]
{
    const int i0 = blockIdx.y * TI;
    const int k0 = blockIdx.x * TK;
    const int t = threadIdx.x;

    __shared__ __align__(16) float4 fi_s[TI][DF / 4 + 1];  // +1 f4 pad
    __shared__ __align__(16) float4 fk_s[TK][DF / 4 + 1];
    __shared__ float4 hi_s[TI], gi_s[TI], ri_s[TI];  // trans+sym, rg+norm, rr+norm
    __shared__ float4 hk_s[TK], gk_s[TK], rk_s[TK];

    if (t < TI) {
        int g = i0 + t;
        hi_s[t] = make_float4(tr[g * 3], tr[g * 3 + 1], tr[g * 3 + 2],
                              (sym[g] == 1) ? 1.f : 0.f);
        float a = rg[g * 3], b = rg[g * 3 + 1], c = rg[g * 3 + 2];
        gi_s[t] = make_float4(a, b, c, fmaxf(sqrtf(a * a + b * b + c * c), EPS_COS));
        float d = rr[g * 3], e = rr[g * 3 + 1], f = rr[g * 3 + 2];
        ri_s[t] = make_float4(d, e, f, fmaxf(sqrtf(d * d + e * e + f * f), EPS_COS));
    } else if (t >= 32 && t < 32 + TK) {
        int g = k0 + (t - 32);
        int tl = t - 32;
        hk_s[tl] = make_float4(tr[g * 3], tr[g * 3 + 1], tr[g * 3 + 2],
                               (sym[g] == 1) ? 1.f : 0.f);
        float a = rg[g * 3], b = rg[g * 3 + 1], c = rg[g * 3 + 2];
        gk_s[tl] = make_float4(a, b, c, fmaxf(sqrtf(a * a + b * b + c * c), EPS_COS));
        float d = rr[g * 3], e = rr[g * 3 + 1], f = rr[g * 3 + 2];
        rk_s[tl] = make_float4(d, e, f, fmaxf(sqrtf(d * d + e * e + f * f), EPS_COS));
    }

    const float4* feat4 = reinterpret_cast<const float4*>(feat);
#pragma unroll
    for (int idx = 0; idx < 2; ++idx) {
        int u = t + idx * 256;            // 0..511 over 16 rows x 32 f4
        int row = u >> 5, c = u & 31;
        fi_s[row][c] = feat4[(i0 + row) * (DF / 4) + c];
        fk_s[row][c] = feat4[(k0 + row) * (DF / 4) + c];
    }
    __syncthreads();

    const int ii = t >> 4, kk = t & 15;
    float sq = 0.f;
#pragma unroll
    for (int d = 0; d < DF / 4; ++d) {
        float4 a = fi_s[ii][d];
        float4 b = fk_s[kk][d];
        float dx = a.x - b.x, dy = a.y - b.y, dz = a.z - b.z, dw = a.w - b.w;
        sq += dx * dx + dy * dy + dz * dz + dw * dw;
    }
    const int gi = i0 + ii, gk = k0 + kk;
    float dist = (sq > 0.f) ? sqrtf(sq) : 0.f;
    float lo = -dist * (1.0f / TEMP);
    float eo = (gi == gk) ? 0.f : expf(lo);

    float4 ha = hi_s[ii], hb = hk_s[kk];
    float s = 0.f;
    {
        float d0 = ha.x - hb.x, d1 = ha.y - hb.y, d2 = ha.z - hb.z;
        float a0 = fabsf(d0), a1 = fabsf(d1), a2 = fabsf(d2);
        s += (a0 < BETA) ? (0.5f * d0 * d0 / BETA) : (a0 - 0.5f * BETA);
        s += (a1 < BETA) ? (0.5f * d1 * d1 / BETA) : (a1 - 0.5f * BETA);
        s += (a2 < BETA) ? (0.5f * d2 * d2 / BETA) : (a2 - 0.5f * BETA);
    }
    float td = s * (1.0f / 3.0f);

    float4 ga = gi_s[ii], gb = gk_s[kk];
    float gdiff = 1.0f - (ga.x * gb.x + ga.y * gb.y + ga.z * gb.z) / (ga.w * gb.w);
    float4 ra = ri_s[ii], rb = rk_s[kk];
    float rdiff = 1.0f - (ra.x * rb.x + ra.y * rb.y + ra.z * rb.z) / (ra.w * rb.w);
    bool pair_sym = (ha.w != 0.f) || (hb.w != 0.f);
    float rd = pair_sym ? gdiff : (gdiff + rdiff);

    pk[gi * N + gk] = make_float4(td, rd, eo, lo);
}

// ---------------------------------------------------------------------------
// Kernel B: rank denominators + pos terms. 768 blocks (row i = b>>1, j-half
// h = b&1) x 512 threads (8 waves). Lane l holds 3 j's in registers; wave w
// covers k in [w*48, w*48+48). One broadcast ds_read_b128 per k serves 6
// accumulator chains. 24 waves of work per CU for latency hiding.
// ---------------------------------------------------------------------------
__global__ __launch_bounds__(512) void rnc_rank(
    const float4* __restrict__ pk,
    float* __restrict__ partial_h,    // [768]
    float* __restrict__ partial_t)    // [768]
{
    const int i = blockIdx.x >> 1;
    const int h = blockIdx.x & 1;
    const int t = threadIdx.x;

    __shared__ __align__(16) float4 pks[N];      // 6 KB
    __shared__ __align__(16) float2 dp[192][8];  // 12 KB: [j_local][wave]
    __shared__ float red_h[8], red_t[8];

    if (t < N) pks[t] = pk[i * N + t];
    __syncthreads();

    const int w = t >> 6, l = t & 63;
    const int jl = l * 3;                 // local j base 0..189
    float tdj[3], rdj[3];
    float dent[3] = {0.f, 0.f, 0.f};
    float denh[3] = {0.f, 0.f, 0.f};
#pragma unroll
    for (int jj = 0; jj < 3; ++jj) {
        float4 p = pks[h * 192 + jl + jj];
        tdj[jj] = p.x;
        rdj[jj] = p.y;
    }
    const int k0 = w * 48;
#pragma unroll 4
    for (int k = k0; k < k0 + 48; ++k) {
        float4 p = pks[k];  // wave-uniform -> broadcast
#pragma unroll
        for (int jj = 0; jj < 3; ++jj) {
            bool mt = p.x >= tdj[jj];
            bool mh = mt && (p.y >= rdj[jj]);
            dent[jj] += mt ? p.z : 0.f;
            denh[jj] += mh ? p.z : 0.f;
        }
    }
#pragma unroll
    for (int jj = 0; jj < 3; ++jj) dp[jl + jj][w] = make_float2(dent[jj], denh[jj]);
    __syncthreads();

    float pos_h = 0.f, pos_t = 0.f;
    if (t < 192) {
        const int j = h * 192 + t;
        if (j != i) {
            float st_ = 0.f, sh_ = 0.f;
#pragma unroll
            for (int g = 0; g < 8; ++g) {
                float2 v = dp[t][g];
                st_ += v.x;
                sh_ += v.y;
            }
            float lo = pks[j].w;
            pos_h = lo - logf(sh_ + EPS_LOG);
            pos_t = lo - logf(st_ + EPS_LOG);
        }
    }
#pragma unroll
    for (int off = 32; off > 0; off >>= 1) {
        pos_h += __shfl_down(pos_h, off, 64);
        pos_t += __shfl_down(pos_t, off, 64);
    }
    if (l == 0) {
        red_h[w] = pos_h;
        red_t[w] = pos_t;
    }
    __syncthreads();
    if (t == 0) {
        float sh = 0.f, st = 0.f;
#pragma unroll
        for (int g = 0; g < 8; ++g) {
            sh += red_h[g];
            st += red_t[g];
        }
        partial_h[blockIdx.x] = sh;
        partial_t[blockIdx.x] = st;
    }
}

__global__ __launch_bounds__(768) void rnc_final(
    const float* __restrict__ partial_h,
    const float* __restrict__ partial_t,
    float* __restrict__ out)
{
    const int t = threadIdx.x;
    float hsum = partial_h[t];
    float tsum = partial_t[t];
#pragma unroll
    for (int off = 32; off > 0; off >>= 1) {
        hsum += __shfl_down(hsum, off, 64);
        tsum += __shfl_down(tsum, off, 64);
    }
    __shared__ float rh[12], rt[12];
    const int wave = t >> 6, lane = t & 63;
    if (lane == 0) {
        rh[wave] = hsum;
        rt[wave] = tsum;
    }
    __syncthreads();
    if (t == 0) {
        double sh = 0.0, st = 0.0;
#pragma unroll
        for (int w = 0; w < 12; ++w) {
            sh += (double)rh[w];
            st += (double)rt[w];
        }
        const double denom = (double)N * (double)(N - 1);
        out[0] = (float)(-(sh + (double)SOFT_LAMBDA * st) / denom);
    }
}

extern "C" void kernel_launch(void* const* d_in, const int* in_sizes, int n_in,
                              void* d_out, int out_size, void* d_ws, size_t ws_size,
                              hipStream_t stream) {
    const float* feat = (const float*)d_in[0];  // [384,128]
    const float* rg   = (const float*)d_in[1];  // [384,3]
    const float* rr   = (const float*)d_in[2];  // [384,3]
    const float* tr   = (const float*)d_in[3];  // [384,3]
    const int*   sym  = (const int*)d_in[4];    // [384,1]
    float* out = (float*)d_out;

    float4* pk = (float4*)d_ws;                                   // 384*384*16 B
    float* partial_h = (float*)((char*)d_ws + (size_t)N * N * sizeof(float4));
    float* partial_t = partial_h + 2 * N;

    dim3 gridA(N / TK, N / TI);
    rnc_pairs<<<gridA, 256, 0, stream>>>(feat, rg, rr, tr, sym, pk);
    rnc_rank<<<2 * N, 512, 0, stream>>>(pk, partial_h, partial_t);
    rnc_final<<<1, 2 * N, 0, stream>>>(partial_h, partial_t, out);
}